// Round 12
// baseline (408.501 us; speedup 1.0000x reference)
//
#include <hip/hip_runtime.h>
#include <hip/hip_bf16.h>

// Problem constants
#define BB 8
#define NN 16384
#define MM 4096
#define C1 64
#define C2 256
#define K1 320            // C1 + C2
#define CO 256
#define MTOT (BB * NN)    // 131072

// Workspace layout (bytes)
#define STATS_OFF 0                 // 8*256 floats
#define FLAG_OFF  8192
#define W1B_OFF   16384             // bf16 256x320
#define W2B_OFF   180224            // bf16 256x256
#define F2T_OFF   327680            // bf16 [B,M,C2] = 16777216 B
#define XT_OFF    (327680 + 16777216)              // bf16 [MTOT,320]
#define H2_OFF    (327680 + 16777216 + 83886080)   // bf16 [B,CO,N]

// Session ledger:
// - Global column-chunk swizzle + LINEAR-source global_load_lds => conflict-
//   free LDS, fast DMA (r4). Swizzled SOURCE on gload_lds = 4x poison (r1/r2).
// - Counted-vmcnt is safe ONLY with: pure vmem queue (DMA ops only),
//   sched_barrier(0) fences, lgkmcnt(0) before publishing barriers.
//   r5 (impure queue, no fences) raced; r11 (gemm1, disciplined) passed, -8.5us.
// - r12: same recipe in gemm2 - all 4 A-tiles preloaded to regs in prologue
//   (queue pure in steady state) + v_cvt_pk_bf16_f32 for the BN convert.

typedef short v8s __attribute__((ext_vector_type(8)));
typedef float v4f __attribute__((ext_vector_type(4)));

__device__ __forceinline__ float bf2f(unsigned short u) {
    unsigned v = ((unsigned)u) << 16;
    float f;
    __builtin_memcpy(&f, &v, 4);
    return f;
}
__device__ __forceinline__ unsigned short f2bf(float f) {
    unsigned u;
    __builtin_memcpy(&u, &f, 4);
    unsigned r = u + 0x7fffu + ((u >> 16) & 1u);  // RNE
    return (unsigned short)(r >> 16);
}
__device__ __forceinline__ void gload16(const unsigned short* g, unsigned short* l) {
    __builtin_amdgcn_global_load_lds((const __attribute__((address_space(1))) unsigned int*)g,
                                     (__attribute__((address_space(3))) unsigned int*)l, 16, 0, 0);
}

// ========== fused pre-pass: prep (weights->bf16 swizzled, stats zero, idx
// width flag) + f2 transpose + f1 transpose. Independent block ranges. =======
__global__ void k_pre(const void* idx_raw, int* flag64, float* stats,
                      const float* __restrict__ W1, unsigned short* __restrict__ W1b,
                      const float* __restrict__ W2, unsigned short* __restrict__ W2b,
                      const float* __restrict__ f2, unsigned short* __restrict__ f2t,
                      const float* __restrict__ f1, unsigned short* __restrict__ xT) {
    __shared__ float tile[64][33];
    int blk = blockIdx.x;
    int t = threadIdx.x;
    if (blk < 320) {
        // W1 -> bf16, column-chunk swizzled: col' = col ^ ((row&7)<<3)
        int e = blk * 256 + t;
        int row = e / K1, col = e - row * K1;
        W1b[row * K1 + (col ^ ((row & 7) << 3))] = f2bf(W1[e]);
    } else if (blk < 576) {
        int e = (blk - 320) * 256 + t;
        int row = e >> 8, col = e & 255;
        W2b[row * CO + (col ^ ((row & 7) << 3))] = f2bf(W2[e]);
    } else if (blk == 576) {
        for (int i = t; i < 8 * 256; i += 256) stats[i] = 0.f;
        if (t == 0) {
            const int* a = (const int*)idx_raw;
            int all0 = 1;
            for (int j = 1; j < 64; j += 2) all0 &= (a[j] == 0);
            *flag64 = all0;  // 1 => idx int64
        }
    } else if (blk < 577 + 4096) {
        // ---- f2 [B,C2,M] -> f2t bf16 [B,M,C2]; 64ch x 32m tiles (no swizzle)
        int i = blk - 577;
        int m0 = (i & 127) * 32;
        int c0 = ((i >> 7) & 3) * 64;
        int b = i >> 9;
        int lm = t & 31, lc = t >> 5;          // lc 0..7
        const float* src = f2 + ((size_t)b * C2 + c0) * MM + m0;
#pragma unroll
        for (int j = 0; j < 8; ++j)
            tile[lc + 8 * j][lm] = src[(size_t)(lc + 8 * j) * MM + lm];
        __syncthreads();
        int m = t >> 3, c8 = (t & 7) * 8;      // m 0..31, c8 0..56
        unsigned short tmp[8];
#pragma unroll
        for (int k = 0; k < 8; ++k) tmp[k] = f2bf(tile[c8 + k][m]);
        uint4 v;
        v.x = (unsigned)tmp[0] | ((unsigned)tmp[1] << 16);
        v.y = (unsigned)tmp[2] | ((unsigned)tmp[3] << 16);
        v.z = (unsigned)tmp[4] | ((unsigned)tmp[5] << 16);
        v.w = (unsigned)tmp[6] | ((unsigned)tmp[7] << 16);
        *(uint4*)&f2t[((size_t)b * MM + m0 + m) * C2 + c0 + c8] = v;
    } else {
        // ---- f1 [B,C1,N] -> xT[:,0:64] bf16, chunk-swizzled by row ---------
        int i = blk - 4673;
        int n0 = (i & 511) * 32;
        int b = i >> 9;
        int lm = t & 31, lc = t >> 5;
        const float* src = f1 + ((size_t)b * C1) * NN + n0;
#pragma unroll
        for (int j = 0; j < 8; ++j)
            tile[lc + 8 * j][lm] = src[(size_t)(lc + 8 * j) * NN + lm];
        __syncthreads();
        int m = t >> 3, c8 = (t & 7) * 8;
        unsigned short tmp[8];
#pragma unroll
        for (int k = 0; k < 8; ++k) tmp[k] = f2bf(tile[c8 + k][m]);
        uint4 v;
        v.x = (unsigned)tmp[0] | ((unsigned)tmp[1] << 16);
        v.y = (unsigned)tmp[2] | ((unsigned)tmp[3] << 16);
        v.z = (unsigned)tmp[4] | ((unsigned)tmp[5] << 16);
        v.w = (unsigned)tmp[6] | ((unsigned)tmp[7] << 16);
        // row = n0+m; (row&7) == (m&7) since n0 % 32 == 0
        *(uint4*)&xT[((size_t)b * NN + n0 + m) * K1 + (c8 ^ ((m & 7) * 8))] = v;
    }
}

// ---------------- 3-NN inverse-distance interpolation -> xT[:,64:320] -------
__global__ void k_interp(const float* __restrict__ p1, const float* __restrict__ p2,
                         const void* __restrict__ idxv, const int* __restrict__ flag64,
                         const unsigned short* __restrict__ f2t,
                         unsigned short* __restrict__ xT) {
    int t = threadIdx.x;
    int p = t >> 5, lane = t & 31;
    size_t pt = (size_t)blockIdx.x * 8 + p;
    int b = (int)(pt >> 14);
    int m0, m1, m2;
    if (*flag64) {
        const long long* id = (const long long*)idxv;
        m0 = (int)id[pt * 3 + 0]; m1 = (int)id[pt * 3 + 1]; m2 = (int)id[pt * 3 + 2];
    } else {
        const int* id = (const int*)idxv;
        m0 = id[pt * 3 + 0]; m1 = id[pt * 3 + 1]; m2 = id[pt * 3 + 2];
    }
    float qx = p1[pt * 3 + 0], qy = p1[pt * 3 + 1], qz = p1[pt * 3 + 2];
    const float* pb = p2 + (size_t)b * MM * 3;
    float dx, dy, dz;
    dx = qx - pb[m0 * 3 + 0]; dy = qy - pb[m0 * 3 + 1]; dz = qz - pb[m0 * 3 + 2];
    float d0 = dx * dx + dy * dy + dz * dz;
    dx = qx - pb[m1 * 3 + 0]; dy = qy - pb[m1 * 3 + 1]; dz = qz - pb[m1 * 3 + 2];
    float d1 = dx * dx + dy * dy + dz * dz;
    dx = qx - pb[m2 * 3 + 0]; dy = qy - pb[m2 * 3 + 1]; dz = qz - pb[m2 * 3 + 2];
    float d2v = dx * dx + dy * dy + dz * dz;
    float r0 = 1.f / (d0 + 1e-8f), r1 = 1.f / (d1 + 1e-8f), r2 = 1.f / (d2v + 1e-8f);
    float inv = 1.f / (r0 + r1 + r2);
    float w0 = r0 * inv, w1 = r1 * inv, w2 = r2 * inv;

    const unsigned short* fb = f2t + (size_t)b * MM * C2;
    int c0 = lane * 8;
    uint4 va = *(const uint4*)(fb + (size_t)m0 * C2 + c0);
    uint4 vb = *(const uint4*)(fb + (size_t)m1 * C2 + c0);
    uint4 vc = *(const uint4*)(fb + (size_t)m2 * C2 + c0);

    float r[8];
    {
        const unsigned av[4] = {va.x, va.y, va.z, va.w};
        const unsigned bv[4] = {vb.x, vb.y, vb.z, vb.w};
        const unsigned cv[4] = {vc.x, vc.y, vc.z, vc.w};
#pragma unroll
        for (int q = 0; q < 4; ++q) {
            r[2 * q + 0] = w0 * bf2f((unsigned short)(av[q] & 0xffff))
                         + w1 * bf2f((unsigned short)(bv[q] & 0xffff))
                         + w2 * bf2f((unsigned short)(cv[q] & 0xffff));
            r[2 * q + 1] = w0 * bf2f((unsigned short)(av[q] >> 16))
                         + w1 * bf2f((unsigned short)(bv[q] >> 16))
                         + w2 * bf2f((unsigned short)(cv[q] >> 16));
        }
    }
    uint4 outv;
    outv.x = (unsigned)f2bf(r[0]) | ((unsigned)f2bf(r[1]) << 16);
    outv.y = (unsigned)f2bf(r[2]) | ((unsigned)f2bf(r[3]) << 16);
    outv.z = (unsigned)f2bf(r[4]) | ((unsigned)f2bf(r[5]) << 16);
    outv.w = (unsigned)f2bf(r[6]) | ((unsigned)f2bf(r[7]) << 16);
    // chunk-swizzle by point row: col' = col ^ ((pt&7)*8) (stays in 64-col group)
    *(uint4*)(xT + pt * K1 + ((C1 + c0) ^ (((int)pt & 7) * 8))) = outv;
}

// ================= MFMA GEMM1: h1 = xT @ W1^T (bf16), + BN1 stats ==========
// r11 counted-vmcnt double buffer (verified). Pure queue (8 DMA/iter only).
#define TM 128
#define TN 128
#define TK 64
__launch_bounds__(256)
__global__ void k_gemm1(const unsigned short* __restrict__ xT,
                        const unsigned short* __restrict__ W1b,
                        unsigned short* __restrict__ h1,
                        float* __restrict__ sum1, float* __restrict__ ssq1) {
    __shared__ unsigned short smem[2][TM * TK + TN * TK];   // [buf][ As | Bs ] = 64 KB
    const int t = threadIdx.x;
    const int lane = t & 63, w = t >> 6;
    const int wm = w >> 1, wc = w & 1;
    const long rbase = (long)blockIdx.y * TM;
    const int cb = blockIdx.x * TN;

    v4f acc[4][4];
#pragma unroll
    for (int r = 0; r < 4; ++r)
#pragma unroll
        for (int c = 0; c < 4; ++c) acc[r][c] = (v4f)(0.f);

    const int srow = w * 32 + (lane >> 3);
    const int sch = (lane & 7) * 8;          // LINEAR source col (monotone DMA)
    const unsigned short* Ag = xT + (rbase + srow) * K1 + sch;
    const unsigned short* Bg = W1b + (size_t)(cb + srow) * K1 + sch;

    const int ln = lane & 15, q = lane >> 4;
    const int xs = (ln & 7) * 8;             // read-side XOR: (row&7)*8

    // prologue: tile 0 into buf 0 (8 loads in flight)
#pragma unroll
    for (int j = 0; j < 4; ++j) {
        gload16(Ag + (size_t)(j * 8) * K1, smem[0] + (w * 32 + j * 8) * TK);
        gload16(Bg + (size_t)(j * 8) * K1, smem[0] + TM * TK + (w * 32 + j * 8) * TK);
    }

    for (int k0 = 0; k0 < K1; k0 += TK) {
        const int p = (k0 >> 6) & 1;
        if (k0 + TK < K1) {
            // stage tile k+1 into the other buffer; stays in flight across barrier
#pragma unroll
            for (int j = 0; j < 4; ++j) {
                gload16(Ag + (size_t)(j * 8) * K1 + k0 + TK, smem[p ^ 1] + (w * 32 + j * 8) * TK);
                gload16(Bg + (size_t)(j * 8) * K1 + k0 + TK, smem[p ^ 1] + TM * TK + (w * 32 + j * 8) * TK);
            }
            // outstanding: tile k (8 oldest) + tile k+1 (8) -> wait tile k only
            asm volatile("s_waitcnt vmcnt(8)" ::: "memory");
        } else {
            asm volatile("s_waitcnt vmcnt(0)" ::: "memory");
        }
        asm volatile("s_barrier" ::: "memory");   // all waves' tile-k in LDS
        __builtin_amdgcn_sched_barrier(0);        // nothing hoists above the waits
        const unsigned short* ApL = smem[p] + (wm * 64 + ln) * TK;
        const unsigned short* BpL = smem[p] + TM * TK + (wc * 64 + ln) * TK;
#pragma unroll
        for (int ks = 0; ks < 2; ++ks) {
            const int off = (q * 8 + ks * 32) ^ xs;
            v8s af[4], bg[4];
#pragma unroll
            for (int r = 0; r < 4; ++r) af[r] = *(const v8s*)(ApL + r * 16 * TK + off);
#pragma unroll
            for (int c = 0; c < 4; ++c) bg[c] = *(const v8s*)(BpL + c * 16 * TK + off);
#pragma unroll
            for (int r = 0; r < 4; ++r)
#pragma unroll
                for (int c = 0; c < 4; ++c)
                    acc[r][c] = __builtin_amdgcn_mfma_f32_16x16x32_bf16(af[r], bg[c], acc[r][c], 0, 0, 0);
        }
        __builtin_amdgcn_sched_barrier(0);        // ds_reads stay above barrier B
        // protect buf p from next iteration's staging (reads done in all waves)
        if (k0 + TK < K1) asm volatile("s_barrier" ::: "memory");
    }
    __syncthreads();   // drain + collective barrier before epilogue smem reuse

    // ---- epilogue: reg stats + XOR-swizzled LDS transpose -> coalesced stores
    unsigned short* ep = (unsigned short*)smem;   // 128x128 bf16 tile (32 KB)
#pragma unroll
    for (int c = 0; c < 4; ++c) {
        int col = wc * 64 + c * 16 + ln;            // local col 0..127
        int cc = col >> 3, ci = col & 7;
        float s = 0.f, sq = 0.f;
#pragma unroll
        for (int r = 0; r < 4; ++r)
#pragma unroll
            for (int i = 0; i < 4; ++i) {
                int row = wm * 64 + r * 16 + q * 4 + i;
                float v = acc[r][c][i];
                ep[row * 128 + 8 * (cc ^ (row & 15)) + ci] = f2bf(v);
                s += v; sq += v * v;
            }
        // reduce over q (lane bits 4,5); lanes<16 hold per-col totals
        s += __shfl_xor(s, 16); sq += __shfl_xor(sq, 16);
        s += __shfl_xor(s, 32); sq += __shfl_xor(sq, 32);
        if (lane < 16) {
            atomicAdd(&sum1[cb + col], s);
            atomicAdd(&ssq1[cb + col], sq);
        }
    }
    __syncthreads();
    {
        int rr = t >> 4, cc2 = t & 15;
#pragma unroll
        for (int j = 0; j < 8; ++j) {
            int row = rr + 16 * j;
            uint4 v = *(const uint4*)&ep[row * 128 + 8 * (cc2 ^ (row & 15))];
            *(uint4*)&h1[(size_t)(rbase + row) * CO + cb + cc2 * 8] = v;
        }
    }
}

// ====== MFMA GEMM2: h2 = relu(bn1(h1)) @ W2^T -> [B,CO,N] + BN2 stats =======
// r12: counted-vmcnt with PURE steady-state queue. All 4 A-tiles preloaded to
// regs in the prologue (drained there); loop vmem = 4 B-DMA/iter only, so
// vmcnt(4) is exact. CONV (BN1+ReLU via v_cvt_pk_bf16_f32) writes As[p^1]
// whose readers all finished before the previous barrier. lgkmcnt(0)
// publishes ds_writes before each ending barrier. sched_barrier fences per
// rule #18 / r11 recipe.
__launch_bounds__(256)
__global__ void k_gemm2(const unsigned short* __restrict__ h1,
                        const unsigned short* __restrict__ W2b,
                        const float* __restrict__ sum1, const float* __restrict__ ssq1,
                        const float* __restrict__ g1, const float* __restrict__ b1,
                        unsigned short* __restrict__ h2,
                        float* __restrict__ sum2, float* __restrict__ ssq2) {
    __shared__ unsigned short smem[2][TM * TK + TN * TK];   // 64 KB
    __shared__ float sc1[CO], sh1[CO];
    const int t = threadIdx.x;
    const int lane = t & 63, w = t >> 6;
    const int wm = w >> 1, wc = w & 1;
    const long rbase = (long)blockIdx.y * TM;
    const int cb = blockIdx.x * TN;

    // fold BN1 finalize (stream-ordered after gemm1)
    {
        const float invn = 1.f / (float)MTOT;
        float m = sum1[t] * invn;
        float v = ssq1[t] * invn - m * m;
        float s = g1[t] * rsqrtf(v + 1e-5f);
        sc1[t] = s;
        sh1[t] = b1[t] - m * s;
    }

    v4f acc[4][4];
#pragma unroll
    for (int r = 0; r < 4; ++r)
#pragma unroll
        for (int c = 0; c < 4; ++c) acc[r][c] = (v4f)(0.f);

    const int srow = w * 32 + (lane >> 3);
    const int sch = (lane & 7) * 8;
    const unsigned short* Ag = h1 + (rbase + srow) * CO + sch;
    const unsigned short* Bg = W2b + (size_t)(cb + srow) * CO + sch;
    const int awz = srow * TK + (sch ^ ((srow & 7) * 8));   // A ds_write slot

    const int ln = lane & 15, q = lane >> 4;
    const int xs = (ln & 7) * 8;

    // BN1+ReLU convert of one A reg-tile -> swizzled ds_write (cvt_pk packs)
#define CONV_STORE(AV, KOFF, BASE)                                                     \
    do {                                                                               \
        float4 sca = *(const float4*)(sc1 + (KOFF) + sch);                             \
        float4 scb = *(const float4*)(sc1 + (KOFF) + sch + 4);                         \
        float4 sha = *(const float4*)(sh1 + (KOFF) + sch);                             \
        float4 shb = *(const float4*)(sh1 + (KOFF) + sch + 4);                         \
        _Pragma("unroll")                                                              \
        for (int j = 0; j < 4; ++j) {                                                  \
            uint4 av = (AV)[j];                                                        \
            float y0 = fmaxf(bf2f((unsigned short)(av.x & 0xffff)) * sca.x + sha.x, 0.f); \
            float y1 = fmaxf(bf2f((unsigned short)(av.x >> 16)) * sca.y + sha.y, 0.f); \
            float y2 = fmaxf(bf2f((unsigned short)(av.y & 0xffff)) * sca.z + sha.z, 0.f); \
            float y3 = fmaxf(bf2f((unsigned short)(av.y >> 16)) * sca.w + sha.w, 0.f); \
            float y4 = fmaxf(bf2f((unsigned short)(av.z & 0xffff)) * scb.x + shb.x, 0.f); \
            float y5 = fmaxf(bf2f((unsigned short)(av.z >> 16)) * scb.y + shb.y, 0.f); \
            float y6 = fmaxf(bf2f((unsigned short)(av.w & 0xffff)) * scb.z + shb.z, 0.f); \
            float y7 = fmaxf(bf2f((unsigned short)(av.w >> 16)) * scb.w + shb.w, 0.f); \
            uint4 ov;                                                                  \
            asm("v_cvt_pk_bf16_f32 %0, %1, %2" : "=v"(ov.x) : "v"(y0), "v"(y1));       \
            asm("v_cvt_pk_bf16_f32 %0, %1, %2" : "=v"(ov.y) : "v"(y2), "v"(y3));       \
            asm("v_cvt_pk_bf16_f32 %0, %1, %2" : "=v"(ov.z) : "v"(y4), "v"(y5));       \
            asm("v_cvt_pk_bf16_f32 %0, %1, %2" : "=v"(ov.w) : "v"(y6), "v"(y7));       \
            *(uint4*)((BASE) + awz + (j * 8) * TK) = ov;                               \
        }                                                                              \
    } while (0)

    // prologue: B(0) DMA -> Bs[0]; ALL 4 A-tiles -> regs; publish sc1; convert
    // A(0) -> As[0]; full drain. After this the vmem queue is EMPTY.
    uint4 a[4][4];
#pragma unroll
    for (int j = 0; j < 4; ++j)
        gload16(Bg + (size_t)(j * 8) * CO, smem[0] + TM * TK + (w * 32 + j * 8) * TK);
#pragma unroll
    for (int kk = 0; kk < 4; ++kk)
#pragma unroll
        for (int j = 0; j < 4; ++j)
            a[kk][j] = *(const uint4*)(Ag + (size_t)(j * 8) * CO + kk * TK);
    __syncthreads();                 // publish sc1/sh1 (also drains B(0)+A loads)
    CONV_STORE(a[0], 0, smem[0]);
    __syncthreads();                 // publish As[0] ds_writes

    // steady loop, fully unrolled; queue = B-DMA only
#define G2_ITER(KK, P)                                                                 \
    do {                                                                               \
        if ((KK) < 3) {                                                                \
            _Pragma("unroll")                                                          \
            for (int j = 0; j < 4; ++j)                                                \
                gload16(Bg + (size_t)(j * 8) * CO + ((KK) + 1) * TK,                   \
                        smem[(P) ^ 1] + TM * TK + (w * 32 + j * 8) * TK);              \
            CONV_STORE(a[(KK) + 1], ((KK) + 1) * TK, smem[(P) ^ 1]);                   \
            asm volatile("s_waitcnt vmcnt(4)" ::: "memory");                           \
        } else {                                                                       \
            asm volatile("s_waitcnt vmcnt(0)" ::: "memory");                           \
        }                                                                              \
        asm volatile("s_barrier" ::: "memory");                                        \
        __builtin_amdgcn_sched_barrier(0);                                             \
        {                                                                              \
            const unsigned short* ApL = smem[P] + (wm * 64 + ln) * TK;                 \
            const unsigned short* BpL = smem[P] + TM * TK + (wc * 64 + ln) * TK;       \
            _Pragma("unroll")                                                          \
            for (int ks = 0; ks < 2; ++ks) {                                           \
                const int off = (q * 8 + ks * 32) ^ xs;                                \
                v8s af[4], bg4[4];                                                     \
                _Pragma("unroll")                                                      \
                for (int r = 0; r < 4; ++r) af[r] = *(const v8s*)(ApL + r * 16 * TK + off); \
                _Pragma("unroll")                                                      \
                for (int c = 0; c < 4; ++c) bg4[c] = *(const v8s*)(BpL + c * 16 * TK + off); \
                _Pragma("unroll")                                                      \
                for (int r = 0; r < 4; ++r)                                            \
                    _Pragma("unroll")                                                  \
                    for (int c = 0; c < 4; ++c)                                        \
                        acc[r][c] = __builtin_amdgcn_mfma_f32_16x16x32_bf16(af[r], bg4[c], acc[r][c], 0, 0, 0); \
            }                                                                          \
        }                                                                              \
        __builtin_amdgcn_sched_barrier(0);                                             \
        asm volatile("s_waitcnt lgkmcnt(0)" ::: "memory");                             \
        if ((KK) < 3) asm volatile("s_barrier" ::: "memory");                          \
    } while (0)

    G2_ITER(0, 0);
    G2_ITER(1, 1);
    G2_ITER(2, 0);
    G2_ITER(3, 1);
#undef G2_ITER
#undef CONV_STORE
    __syncthreads();   // collective barrier before epilogue smem reuse

    // ---- epilogue: reg stats + transposed swizzled tile -> n-contiguous stores
    unsigned short* ep = (unsigned short*)smem;
    const int b = (int)(rbase >> 14);
    const int nb = (int)(rbase & (NN - 1));
#pragma unroll
    for (int c = 0; c < 4; ++c) {
        int ol = wc * 64 + c * 16 + ln;             // local out-channel 0..127
        float s = 0.f, sq = 0.f;
#pragma unroll
        for (int r = 0; r < 4; ++r)
#pragma unroll
            for (int i = 0; i < 4; ++i) {
                int row = wm * 64 + r * 16 + q * 4 + i;  // local n
                int rc = row >> 3, ri = row & 7;
                float v = acc[r][c][i];
                ep[ol * 128 + 8 * (rc ^ (ol & 15)) + ri] = f2bf(v);
                s += v; sq += v * v;
            }
        s += __shfl_xor(s, 16); sq += __shfl_xor(sq, 16);
        s += __shfl_xor(s, 32); sq += __shfl_xor(sq, 32);
        if (lane < 16) {
            atomicAdd(&sum2[cb + ol], s);
            atomicAdd(&ssq2[cb + ol], sq);
        }
    }
    __syncthreads();
    {
        int oo = t >> 4, nc = t & 15;
#pragma unroll
        for (int j = 0; j < 8; ++j) {
            int ol = oo + 16 * j;
            uint4 v = *(const uint4*)&ep[ol * 128 + 8 * (nc ^ (ol & 15))];
            *(uint4*)&h2[(((size_t)(b * CO + cb + ol)) << 14) + nb + nc * 8] = v;
        }
    }
}

// ---------------- final BN2+ReLU -> fp32 out (BN2 finalize folded) ----------
// 16B bf16 loads (uint4) + 2x float4 stores, 8 floats/lane. Grid =
// out_size/2048 = 16384 blocks; each block spans 2048 elems in one channel.
__global__ void k_apply(const unsigned short* __restrict__ h2,
                        const float* __restrict__ sum2, const float* __restrict__ ssq2,
                        const float* __restrict__ g2, const float* __restrict__ b2,
                        float* __restrict__ out) {
    __shared__ float ss[2];
    int o = (blockIdx.x >> 3) & 255;   // channel = blockIdx.x>>3 (2048 elems/block)
    if (threadIdx.x == 0) {
        const float invn = 1.f / (float)MTOT;
        float m = sum2[o] * invn;
        float v = ssq2[o] * invn - m * m;
        float s = g2[o] * rsqrtf(v + 1e-5f);
        ss[0] = s;
        ss[1] = b2[o] - m * s;
    }
    __syncthreads();
    float s = ss[0], d = ss[1];
    size_t i = ((size_t)blockIdx.x * 256 + threadIdx.x) * 8;
    uint4 hv = *(const uint4*)(h2 + i);
    float4 v0, v1;
    v0.x = fmaxf(bf2f((unsigned short)(hv.x & 0xffff)) * s + d, 0.f);
    v0.y = fmaxf(bf2f((unsigned short)(hv.x >> 16)) * s + d, 0.f);
    v0.z = fmaxf(bf2f((unsigned short)(hv.y & 0xffff)) * s + d, 0.f);
    v0.w = fmaxf(bf2f((unsigned short)(hv.y >> 16)) * s + d, 0.f);
    v1.x = fmaxf(bf2f((unsigned short)(hv.z & 0xffff)) * s + d, 0.f);
    v1.y = fmaxf(bf2f((unsigned short)(hv.z >> 16)) * s + d, 0.f);
    v1.z = fmaxf(bf2f((unsigned short)(hv.w & 0xffff)) * s + d, 0.f);
    v1.w = fmaxf(bf2f((unsigned short)(hv.w >> 16)) * s + d, 0.f);
    *(float4*)&out[i] = v0;
    *(float4*)&out[i + 4] = v1;
}

extern "C" void kernel_launch(void* const* d_in, const int* in_sizes, int n_in,
                              void* d_out, int out_size, void* d_ws, size_t ws_size,
                              hipStream_t stream) {
    const float* p1 = (const float*)d_in[0];
    const float* p2 = (const float*)d_in[1];
    const float* f1 = (const float*)d_in[2];
    const float* f2 = (const float*)d_in[3];
    const void*  idx = d_in[4];
    const float* W1 = (const float*)d_in[5];
    const float* g1 = (const float*)d_in[6];
    const float* b1 = (const float*)d_in[7];
    const float* W2 = (const float*)d_in[8];
    const float* g2 = (const float*)d_in[9];
    const float* b2 = (const float*)d_in[10];
    float* out = (float*)d_out;

    char* ws = (char*)d_ws;
    float* stats = (float*)(ws + STATS_OFF);
    float* sum1 = stats + 0;     float* ssq1 = stats + 256;
    float* sum2 = stats + 1024;  float* ssq2 = stats + 1280;
    int* flag64 = (int*)(ws + FLAG_OFF);
    unsigned short* W1b = (unsigned short*)(ws + W1B_OFF);
    unsigned short* W2b = (unsigned short*)(ws + W2B_OFF);
    unsigned short* f2t = (unsigned short*)(ws + F2T_OFF);
    unsigned short* xT  = (unsigned short*)(ws + XT_OFF);
    unsigned short* h2  = (unsigned short*)(ws + H2_OFF);

    unsigned short* h1 = (unsigned short*)d_out;  // 67 MB bf16 scratch in d_out

    k_pre<<<577 + 4096 + 4096, 256, 0, stream>>>(idx, flag64, stats, W1, W1b, W2, W2b,
                                                 f2, f2t, f1, xT);
    k_interp<<<MTOT / 8, 256, 0, stream>>>(p1, p2, idx, flag64, f2t, xT);
    k_gemm1<<<dim3(CO / TN, MTOT / TM), 256, 0, stream>>>(xT, W1b, h1, sum1, ssq1);
    k_gemm2<<<dim3(CO / TN, MTOT / TM), 256, 0, stream>>>(h1, W2b, sum1, ssq1, g1, b1, h2, sum2, ssq2);
    k_apply<<<(int)((size_t)out_size / 2048), 256, 0, stream>>>(h2, sum2, ssq2, g2, b2, out);
}

// Round 13
// 399.330 us; speedup vs baseline: 1.0230x; 1.0230x over previous
//
#include <hip/hip_runtime.h>
#include <hip/hip_bf16.h>

// Problem constants
#define BB 8
#define NN 16384
#define MM 4096
#define C1 64
#define C2 256
#define K1 320            // C1 + C2
#define CO 256
#define MTOT (BB * NN)    // 131072

// Workspace layout (bytes)
#define STATS_OFF 0                 // 8*256 floats
#define FLAG_OFF  8192
#define W1B_OFF   16384             // bf16 256x320
#define W2B_OFF   180224            // bf16 256x256
#define F2T_OFF   327680            // bf16 [B,M,C2] = 16777216 B
#define XT_OFF    (327680 + 16777216)              // bf16 [MTOT,320]
#define H2_OFF    (327680 + 16777216 + 83886080)   // bf16 [B,CO,N]

// Session ledger:
// - Global column-chunk swizzle + LINEAR-source global_load_lds => conflict-
//   free LDS, fast DMA (r4). Swizzled SOURCE on gload_lds = 4x poison (r1/r2).
// - Counted-vmcnt safe recipe: pure vmem queue + sched_barrier(0) fences +
//   lgkmcnt(0) before publishing barriers. r11 gemm1: -8.5us, verified.
// - r12: gemm2 pure-queue via 4-tile A preload REGRESSED (-8.5us): 64 extra
//   VGPR stepped past the 128-VGPR occupancy cliff + serial prologue. Queue
//   purity via full preload is net-negative at acc=64. Reverted.
// - r13: gemm2 = r7 syncthreads schedule + v_cvt_pk_bf16_f32 convert only.

typedef short v8s __attribute__((ext_vector_type(8)));
typedef float v4f __attribute__((ext_vector_type(4)));

__device__ __forceinline__ float bf2f(unsigned short u) {
    unsigned v = ((unsigned)u) << 16;
    float f;
    __builtin_memcpy(&f, &v, 4);
    return f;
}
__device__ __forceinline__ unsigned short f2bf(float f) {
    unsigned u;
    __builtin_memcpy(&u, &f, 4);
    unsigned r = u + 0x7fffu + ((u >> 16) & 1u);  // RNE
    return (unsigned short)(r >> 16);
}
__device__ __forceinline__ void gload16(const unsigned short* g, unsigned short* l) {
    __builtin_amdgcn_global_load_lds((const __attribute__((address_space(1))) unsigned int*)g,
                                     (__attribute__((address_space(3))) unsigned int*)l, 16, 0, 0);
}

// ========== fused pre-pass: prep (weights->bf16 swizzled, stats zero, idx
// width flag) + f2 transpose + f1 transpose. Independent block ranges. =======
__global__ void k_pre(const void* idx_raw, int* flag64, float* stats,
                      const float* __restrict__ W1, unsigned short* __restrict__ W1b,
                      const float* __restrict__ W2, unsigned short* __restrict__ W2b,
                      const float* __restrict__ f2, unsigned short* __restrict__ f2t,
                      const float* __restrict__ f1, unsigned short* __restrict__ xT) {
    __shared__ float tile[64][33];
    int blk = blockIdx.x;
    int t = threadIdx.x;
    if (blk < 320) {
        // W1 -> bf16, column-chunk swizzled: col' = col ^ ((row&7)<<3)
        int e = blk * 256 + t;
        int row = e / K1, col = e - row * K1;
        W1b[row * K1 + (col ^ ((row & 7) << 3))] = f2bf(W1[e]);
    } else if (blk < 576) {
        int e = (blk - 320) * 256 + t;
        int row = e >> 8, col = e & 255;
        W2b[row * CO + (col ^ ((row & 7) << 3))] = f2bf(W2[e]);
    } else if (blk == 576) {
        for (int i = t; i < 8 * 256; i += 256) stats[i] = 0.f;
        if (t == 0) {
            const int* a = (const int*)idx_raw;
            int all0 = 1;
            for (int j = 1; j < 64; j += 2) all0 &= (a[j] == 0);
            *flag64 = all0;  // 1 => idx int64
        }
    } else if (blk < 577 + 4096) {
        // ---- f2 [B,C2,M] -> f2t bf16 [B,M,C2]; 64ch x 32m tiles (no swizzle)
        int i = blk - 577;
        int m0 = (i & 127) * 32;
        int c0 = ((i >> 7) & 3) * 64;
        int b = i >> 9;
        int lm = t & 31, lc = t >> 5;          // lc 0..7
        const float* src = f2 + ((size_t)b * C2 + c0) * MM + m0;
#pragma unroll
        for (int j = 0; j < 8; ++j)
            tile[lc + 8 * j][lm] = src[(size_t)(lc + 8 * j) * MM + lm];
        __syncthreads();
        int m = t >> 3, c8 = (t & 7) * 8;      // m 0..31, c8 0..56
        unsigned short tmp[8];
#pragma unroll
        for (int k = 0; k < 8; ++k) tmp[k] = f2bf(tile[c8 + k][m]);
        uint4 v;
        v.x = (unsigned)tmp[0] | ((unsigned)tmp[1] << 16);
        v.y = (unsigned)tmp[2] | ((unsigned)tmp[3] << 16);
        v.z = (unsigned)tmp[4] | ((unsigned)tmp[5] << 16);
        v.w = (unsigned)tmp[6] | ((unsigned)tmp[7] << 16);
        *(uint4*)&f2t[((size_t)b * MM + m0 + m) * C2 + c0 + c8] = v;
    } else {
        // ---- f1 [B,C1,N] -> xT[:,0:64] bf16, chunk-swizzled by row ---------
        int i = blk - 4673;
        int n0 = (i & 511) * 32;
        int b = i >> 9;
        int lm = t & 31, lc = t >> 5;
        const float* src = f1 + ((size_t)b * C1) * NN + n0;
#pragma unroll
        for (int j = 0; j < 8; ++j)
            tile[lc + 8 * j][lm] = src[(size_t)(lc + 8 * j) * NN + lm];
        __syncthreads();
        int m = t >> 3, c8 = (t & 7) * 8;
        unsigned short tmp[8];
#pragma unroll
        for (int k = 0; k < 8; ++k) tmp[k] = f2bf(tile[c8 + k][m]);
        uint4 v;
        v.x = (unsigned)tmp[0] | ((unsigned)tmp[1] << 16);
        v.y = (unsigned)tmp[2] | ((unsigned)tmp[3] << 16);
        v.z = (unsigned)tmp[4] | ((unsigned)tmp[5] << 16);
        v.w = (unsigned)tmp[6] | ((unsigned)tmp[7] << 16);
        // row = n0+m; (row&7) == (m&7) since n0 % 32 == 0
        *(uint4*)&xT[((size_t)b * NN + n0 + m) * K1 + (c8 ^ ((m & 7) * 8))] = v;
    }
}

// ---------------- 3-NN inverse-distance interpolation -> xT[:,64:320] -------
__global__ void k_interp(const float* __restrict__ p1, const float* __restrict__ p2,
                         const void* __restrict__ idxv, const int* __restrict__ flag64,
                         const unsigned short* __restrict__ f2t,
                         unsigned short* __restrict__ xT) {
    int t = threadIdx.x;
    int p = t >> 5, lane = t & 31;
    size_t pt = (size_t)blockIdx.x * 8 + p;
    int b = (int)(pt >> 14);
    int m0, m1, m2;
    if (*flag64) {
        const long long* id = (const long long*)idxv;
        m0 = (int)id[pt * 3 + 0]; m1 = (int)id[pt * 3 + 1]; m2 = (int)id[pt * 3 + 2];
    } else {
        const int* id = (const int*)idxv;
        m0 = id[pt * 3 + 0]; m1 = id[pt * 3 + 1]; m2 = id[pt * 3 + 2];
    }
    float qx = p1[pt * 3 + 0], qy = p1[pt * 3 + 1], qz = p1[pt * 3 + 2];
    const float* pb = p2 + (size_t)b * MM * 3;
    float dx, dy, dz;
    dx = qx - pb[m0 * 3 + 0]; dy = qy - pb[m0 * 3 + 1]; dz = qz - pb[m0 * 3 + 2];
    float d0 = dx * dx + dy * dy + dz * dz;
    dx = qx - pb[m1 * 3 + 0]; dy = qy - pb[m1 * 3 + 1]; dz = qz - pb[m1 * 3 + 2];
    float d1 = dx * dx + dy * dy + dz * dz;
    dx = qx - pb[m2 * 3 + 0]; dy = qy - pb[m2 * 3 + 1]; dz = qz - pb[m2 * 3 + 2];
    float d2v = dx * dx + dy * dy + dz * dz;
    float r0 = 1.f / (d0 + 1e-8f), r1 = 1.f / (d1 + 1e-8f), r2 = 1.f / (d2v + 1e-8f);
    float inv = 1.f / (r0 + r1 + r2);
    float w0 = r0 * inv, w1 = r1 * inv, w2 = r2 * inv;

    const unsigned short* fb = f2t + (size_t)b * MM * C2;
    int c0 = lane * 8;
    uint4 va = *(const uint4*)(fb + (size_t)m0 * C2 + c0);
    uint4 vb = *(const uint4*)(fb + (size_t)m1 * C2 + c0);
    uint4 vc = *(const uint4*)(fb + (size_t)m2 * C2 + c0);

    float r[8];
    {
        const unsigned av[4] = {va.x, va.y, va.z, va.w};
        const unsigned bv[4] = {vb.x, vb.y, vb.z, vb.w};
        const unsigned cv[4] = {vc.x, vc.y, vc.z, vc.w};
#pragma unroll
        for (int q = 0; q < 4; ++q) {
            r[2 * q + 0] = w0 * bf2f((unsigned short)(av[q] & 0xffff))
                         + w1 * bf2f((unsigned short)(bv[q] & 0xffff))
                         + w2 * bf2f((unsigned short)(cv[q] & 0xffff));
            r[2 * q + 1] = w0 * bf2f((unsigned short)(av[q] >> 16))
                         + w1 * bf2f((unsigned short)(bv[q] >> 16))
                         + w2 * bf2f((unsigned short)(cv[q] >> 16));
        }
    }
    uint4 outv;
    outv.x = (unsigned)f2bf(r[0]) | ((unsigned)f2bf(r[1]) << 16);
    outv.y = (unsigned)f2bf(r[2]) | ((unsigned)f2bf(r[3]) << 16);
    outv.z = (unsigned)f2bf(r[4]) | ((unsigned)f2bf(r[5]) << 16);
    outv.w = (unsigned)f2bf(r[6]) | ((unsigned)f2bf(r[7]) << 16);
    // chunk-swizzle by point row: col' = col ^ ((pt&7)*8) (stays in 64-col group)
    *(uint4*)(xT + pt * K1 + ((C1 + c0) ^ (((int)pt & 7) * 8))) = outv;
}

// ================= MFMA GEMM1: h1 = xT @ W1^T (bf16), + BN1 stats ==========
// r11 counted-vmcnt double buffer (verified). Pure queue (8 DMA/iter only).
#define TM 128
#define TN 128
#define TK 64
__launch_bounds__(256)
__global__ void k_gemm1(const unsigned short* __restrict__ xT,
                        const unsigned short* __restrict__ W1b,
                        unsigned short* __restrict__ h1,
                        float* __restrict__ sum1, float* __restrict__ ssq1) {
    __shared__ unsigned short smem[2][TM * TK + TN * TK];   // [buf][ As | Bs ] = 64 KB
    const int t = threadIdx.x;
    const int lane = t & 63, w = t >> 6;
    const int wm = w >> 1, wc = w & 1;
    const long rbase = (long)blockIdx.y * TM;
    const int cb = blockIdx.x * TN;

    v4f acc[4][4];
#pragma unroll
    for (int r = 0; r < 4; ++r)
#pragma unroll
        for (int c = 0; c < 4; ++c) acc[r][c] = (v4f)(0.f);

    const int srow = w * 32 + (lane >> 3);
    const int sch = (lane & 7) * 8;          // LINEAR source col (monotone DMA)
    const unsigned short* Ag = xT + (rbase + srow) * K1 + sch;
    const unsigned short* Bg = W1b + (size_t)(cb + srow) * K1 + sch;

    const int ln = lane & 15, q = lane >> 4;
    const int xs = (ln & 7) * 8;             // read-side XOR: (row&7)*8

    // prologue: tile 0 into buf 0 (8 loads in flight)
#pragma unroll
    for (int j = 0; j < 4; ++j) {
        gload16(Ag + (size_t)(j * 8) * K1, smem[0] + (w * 32 + j * 8) * TK);
        gload16(Bg + (size_t)(j * 8) * K1, smem[0] + TM * TK + (w * 32 + j * 8) * TK);
    }

    for (int k0 = 0; k0 < K1; k0 += TK) {
        const int p = (k0 >> 6) & 1;
        if (k0 + TK < K1) {
            // stage tile k+1 into the other buffer; stays in flight across barrier
#pragma unroll
            for (int j = 0; j < 4; ++j) {
                gload16(Ag + (size_t)(j * 8) * K1 + k0 + TK, smem[p ^ 1] + (w * 32 + j * 8) * TK);
                gload16(Bg + (size_t)(j * 8) * K1 + k0 + TK, smem[p ^ 1] + TM * TK + (w * 32 + j * 8) * TK);
            }
            // outstanding: tile k (8 oldest) + tile k+1 (8) -> wait tile k only
            asm volatile("s_waitcnt vmcnt(8)" ::: "memory");
        } else {
            asm volatile("s_waitcnt vmcnt(0)" ::: "memory");
        }
        asm volatile("s_barrier" ::: "memory");   // all waves' tile-k in LDS
        __builtin_amdgcn_sched_barrier(0);        // nothing hoists above the waits
        const unsigned short* ApL = smem[p] + (wm * 64 + ln) * TK;
        const unsigned short* BpL = smem[p] + TM * TK + (wc * 64 + ln) * TK;
#pragma unroll
        for (int ks = 0; ks < 2; ++ks) {
            const int off = (q * 8 + ks * 32) ^ xs;
            v8s af[4], bg[4];
#pragma unroll
            for (int r = 0; r < 4; ++r) af[r] = *(const v8s*)(ApL + r * 16 * TK + off);
#pragma unroll
            for (int c = 0; c < 4; ++c) bg[c] = *(const v8s*)(BpL + c * 16 * TK + off);
#pragma unroll
            for (int r = 0; r < 4; ++r)
#pragma unroll
                for (int c = 0; c < 4; ++c)
                    acc[r][c] = __builtin_amdgcn_mfma_f32_16x16x32_bf16(af[r], bg[c], acc[r][c], 0, 0, 0);
        }
        __builtin_amdgcn_sched_barrier(0);        // ds_reads stay above barrier B
        // protect buf p from next iteration's staging (reads done in all waves)
        if (k0 + TK < K1) asm volatile("s_barrier" ::: "memory");
    }
    __syncthreads();   // drain + collective barrier before epilogue smem reuse

    // ---- epilogue: reg stats + XOR-swizzled LDS transpose -> coalesced stores
    unsigned short* ep = (unsigned short*)smem;   // 128x128 bf16 tile (32 KB)
#pragma unroll
    for (int c = 0; c < 4; ++c) {
        int col = wc * 64 + c * 16 + ln;            // local col 0..127
        int cc = col >> 3, ci = col & 7;
        float s = 0.f, sq = 0.f;
#pragma unroll
        for (int r = 0; r < 4; ++r)
#pragma unroll
            for (int i = 0; i < 4; ++i) {
                int row = wm * 64 + r * 16 + q * 4 + i;
                float v = acc[r][c][i];
                ep[row * 128 + 8 * (cc ^ (row & 15)) + ci] = f2bf(v);
                s += v; sq += v * v;
            }
        // reduce over q (lane bits 4,5); lanes<16 hold per-col totals
        s += __shfl_xor(s, 16); sq += __shfl_xor(sq, 16);
        s += __shfl_xor(s, 32); sq += __shfl_xor(sq, 32);
        if (lane < 16) {
            atomicAdd(&sum1[cb + col], s);
            atomicAdd(&ssq1[cb + col], sq);
        }
    }
    __syncthreads();
    {
        int rr = t >> 4, cc2 = t & 15;
#pragma unroll
        for (int j = 0; j < 8; ++j) {
            int row = rr + 16 * j;
            uint4 v = *(const uint4*)&ep[row * 128 + 8 * (cc2 ^ (row & 15))];
            *(uint4*)&h1[(size_t)(rbase + row) * CO + cb + cc2 * 8] = v;
        }
    }
}

// ====== MFMA GEMM2: h2 = relu(bn1(h1)) @ W2^T -> [B,CO,N] + BN2 stats =======
// r7 schedule (best known for gemm2: syncthreads 2-phase dbuf, convert-ahead
// A pipeline, 88 VGPR) + r12's verified v_cvt_pk_bf16_f32 convert (the only
// retained delta; halves the pack-op count in the hot VALU path).
__launch_bounds__(256)
__global__ void k_gemm2(const unsigned short* __restrict__ h1,
                        const unsigned short* __restrict__ W2b,
                        const float* __restrict__ sum1, const float* __restrict__ ssq1,
                        const float* __restrict__ g1, const float* __restrict__ b1,
                        unsigned short* __restrict__ h2,
                        float* __restrict__ sum2, float* __restrict__ ssq2) {
    __shared__ unsigned short smem[2][TM * TK + TN * TK];   // 64 KB
    __shared__ float sc1[CO], sh1[CO];
    const int t = threadIdx.x;
    const int lane = t & 63, w = t >> 6;
    const int wm = w >> 1, wc = w & 1;
    const long rbase = (long)blockIdx.y * TM;
    const int cb = blockIdx.x * TN;

    // fold BN1 finalize (stream-ordered after gemm1)
    {
        const float invn = 1.f / (float)MTOT;
        float m = sum1[t] * invn;
        float v = ssq1[t] * invn - m * m;
        float s = g1[t] * rsqrtf(v + 1e-5f);
        sc1[t] = s;
        sh1[t] = b1[t] - m * s;
    }
    __syncthreads();

    v4f acc[4][4];
#pragma unroll
    for (int r = 0; r < 4; ++r)
#pragma unroll
        for (int c = 0; c < 4; ++c) acc[r][c] = (v4f)(0.f);

    const int srow = w * 32 + (lane >> 3);
    const int sch = (lane & 7) * 8;
    const unsigned short* Ag = h1 + (rbase + srow) * CO + sch;
    const unsigned short* Bg = W2b + (size_t)(cb + srow) * CO + sch;
    const int awz = srow * TK + (sch ^ ((srow & 7) * 8));   // A ds_write slot

    const int ln = lane & 15, q = lane >> 4;
    const int xs = (ln & 7) * 8;

    // BN1+ReLU convert of one A reg-tile -> swizzled ds_write (cvt_pk packs)
#define CONV_STORE(AV, KOFF, BASE)                                                     \
    do {                                                                               \
        float4 sca = *(const float4*)(sc1 + (KOFF) + sch);                             \
        float4 scb = *(const float4*)(sc1 + (KOFF) + sch + 4);                         \
        float4 sha = *(const float4*)(sh1 + (KOFF) + sch);                             \
        float4 shb = *(const float4*)(sh1 + (KOFF) + sch + 4);                         \
        _Pragma("unroll")                                                              \
        for (int j = 0; j < 4; ++j) {                                                  \
            uint4 av = (AV)[j];                                                        \
            float y0 = fmaxf(bf2f((unsigned short)(av.x & 0xffff)) * sca.x + sha.x, 0.f); \
            float y1 = fmaxf(bf2f((unsigned short)(av.x >> 16)) * sca.y + sha.y, 0.f); \
            float y2 = fmaxf(bf2f((unsigned short)(av.y & 0xffff)) * sca.z + sha.z, 0.f); \
            float y3 = fmaxf(bf2f((unsigned short)(av.y >> 16)) * sca.w + sha.w, 0.f); \
            float y4 = fmaxf(bf2f((unsigned short)(av.z & 0xffff)) * scb.x + shb.x, 0.f); \
            float y5 = fmaxf(bf2f((unsigned short)(av.z >> 16)) * scb.y + shb.y, 0.f); \
            float y6 = fmaxf(bf2f((unsigned short)(av.w & 0xffff)) * scb.z + shb.z, 0.f); \
            float y7 = fmaxf(bf2f((unsigned short)(av.w >> 16)) * scb.w + shb.w, 0.f); \
            uint4 ov;                                                                  \
            asm("v_cvt_pk_bf16_f32 %0, %1, %2" : "=v"(ov.x) : "v"(y0), "v"(y1));       \
            asm("v_cvt_pk_bf16_f32 %0, %1, %2" : "=v"(ov.y) : "v"(y2), "v"(y3));       \
            asm("v_cvt_pk_bf16_f32 %0, %1, %2" : "=v"(ov.z) : "v"(y4), "v"(y5));       \
            asm("v_cvt_pk_bf16_f32 %0, %1, %2" : "=v"(ov.w) : "v"(y6), "v"(y7));       \
            *(uint4*)((BASE) + awz + (j * 8) * TK) = ov;                               \
        }                                                                              \
    } while (0)

    // prologue: B(0) DMA -> Bs[0]; A(0),A(1) regs; convert A(0) -> As[0]; sync
    uint4 avc[4], avn[4];
#pragma unroll
    for (int j = 0; j < 4; ++j)
        gload16(Bg + (size_t)(j * 8) * CO, smem[0] + TM * TK + (w * 32 + j * 8) * TK);
#pragma unroll
    for (int j = 0; j < 4; ++j) avc[j] = *(const uint4*)(Ag + (size_t)(j * 8) * CO);
#pragma unroll
    for (int j = 0; j < 4; ++j) avn[j] = *(const uint4*)(Ag + (size_t)(j * 8) * CO + TK);
    CONV_STORE(avc, 0, smem[0]);
    __syncthreads();

#pragma unroll
    for (int kk = 0; kk < 4; ++kk) {
        const int p = kk & 1;
        if (kk < 3) {
            // issue B(k+1) DMA early (flies during convert + MFMA)
#pragma unroll
            for (int j = 0; j < 4; ++j)
                gload16(Bg + (size_t)(j * 8) * CO + (kk + 1) * TK,
                        smem[p ^ 1] + TM * TK + (w * 32 + j * 8) * TK);
            // convert A(k+1) -> As[p^1] (reads avn, then avn is dead)
            CONV_STORE(avn, (kk + 1) * TK, smem[p ^ 1]);
        }
        if (kk < 2) {
            // reload avn with A(k+2); latency hides under the MFMA phase below
#pragma unroll
            for (int j = 0; j < 4; ++j)
                avn[j] = *(const uint4*)(Ag + (size_t)(j * 8) * CO + (kk + 2) * TK);
        }
        const unsigned short* ApL = smem[p] + (wm * 64 + ln) * TK;
        const unsigned short* BpL = smem[p] + TM * TK + (wc * 64 + ln) * TK;
#pragma unroll
        for (int ks = 0; ks < 2; ++ks) {
            const int off = (q * 8 + ks * 32) ^ xs;
            v8s af[4], bg4[4];
#pragma unroll
            for (int r = 0; r < 4; ++r) af[r] = *(const v8s*)(ApL + r * 16 * TK + off);
#pragma unroll
            for (int c = 0; c < 4; ++c) bg4[c] = *(const v8s*)(BpL + c * 16 * TK + off);
#pragma unroll
            for (int r = 0; r < 4; ++r)
#pragma unroll
                for (int c = 0; c < 4; ++c)
                    acc[r][c] = __builtin_amdgcn_mfma_f32_16x16x32_bf16(af[r], bg4[c], acc[r][c], 0, 0, 0);
        }
        // drains B(k+1) DMA, publishes As[p^1] writes, protects smem[p] reuse
        __syncthreads();
    }
#undef CONV_STORE

    // ---- epilogue: reg stats + transposed swizzled tile -> n-contiguous stores
    unsigned short* ep = (unsigned short*)smem;
    const int b = (int)(rbase >> 14);
    const int nb = (int)(rbase & (NN - 1));
#pragma unroll
    for (int c = 0; c < 4; ++c) {
        int ol = wc * 64 + c * 16 + ln;             // local out-channel 0..127
        float s = 0.f, sq = 0.f;
#pragma unroll
        for (int r = 0; r < 4; ++r)
#pragma unroll
            for (int i = 0; i < 4; ++i) {
                int row = wm * 64 + r * 16 + q * 4 + i;  // local n
                int rc = row >> 3, ri = row & 7;
                float v = acc[r][c][i];
                ep[ol * 128 + 8 * (rc ^ (ol & 15)) + ri] = f2bf(v);
                s += v; sq += v * v;
            }
        s += __shfl_xor(s, 16); sq += __shfl_xor(sq, 16);
        s += __shfl_xor(s, 32); sq += __shfl_xor(sq, 32);
        if (lane < 16) {
            atomicAdd(&sum2[cb + ol], s);
            atomicAdd(&ssq2[cb + ol], sq);
        }
    }
    __syncthreads();
    {
        int oo = t >> 4, nc = t & 15;
#pragma unroll
        for (int j = 0; j < 8; ++j) {
            int ol = oo + 16 * j;
            uint4 v = *(const uint4*)&ep[ol * 128 + 8 * (nc ^ (ol & 15))];
            *(uint4*)&h2[(((size_t)(b * CO + cb + ol)) << 14) + nb + nc * 8] = v;
        }
    }
}

// ---------------- final BN2+ReLU -> fp32 out (BN2 finalize folded) ----------
// 16B bf16 loads (uint4) + 2x float4 stores, 8 floats/lane. Grid =
// out_size/2048 = 16384 blocks; each block spans 2048 elems in one channel.
__global__ void k_apply(const unsigned short* __restrict__ h2,
                        const float* __restrict__ sum2, const float* __restrict__ ssq2,
                        const float* __restrict__ g2, const float* __restrict__ b2,
                        float* __restrict__ out) {
    __shared__ float ss[2];
    int o = (blockIdx.x >> 3) & 255;   // channel = blockIdx.x>>3 (2048 elems/block)
    if (threadIdx.x == 0) {
        const float invn = 1.f / (float)MTOT;
        float m = sum2[o] * invn;
        float v = ssq2[o] * invn - m * m;
        float s = g2[o] * rsqrtf(v + 1e-5f);
        ss[0] = s;
        ss[1] = b2[o] - m * s;
    }
    __syncthreads();
    float s = ss[0], d = ss[1];
    size_t i = ((size_t)blockIdx.x * 256 + threadIdx.x) * 8;
    uint4 hv = *(const uint4*)(h2 + i);
    float4 v0, v1;
    v0.x = fmaxf(bf2f((unsigned short)(hv.x & 0xffff)) * s + d, 0.f);
    v0.y = fmaxf(bf2f((unsigned short)(hv.x >> 16)) * s + d, 0.f);
    v0.z = fmaxf(bf2f((unsigned short)(hv.y & 0xffff)) * s + d, 0.f);
    v0.w = fmaxf(bf2f((unsigned short)(hv.y >> 16)) * s + d, 0.f);
    v1.x = fmaxf(bf2f((unsigned short)(hv.z & 0xffff)) * s + d, 0.f);
    v1.y = fmaxf(bf2f((unsigned short)(hv.z >> 16)) * s + d, 0.f);
    v1.z = fmaxf(bf2f((unsigned short)(hv.w & 0xffff)) * s + d, 0.f);
    v1.w = fmaxf(bf2f((unsigned short)(hv.w >> 16)) * s + d, 0.f);
    *(float4*)&out[i] = v0;
    *(float4*)&out[i + 4] = v1;
}

extern "C" void kernel_launch(void* const* d_in, const int* in_sizes, int n_in,
                              void* d_out, int out_size, void* d_ws, size_t ws_size,
                              hipStream_t stream) {
    const float* p1 = (const float*)d_in[0];
    const float* p2 = (const float*)d_in[1];
    const float* f1 = (const float*)d_in[2];
    const float* f2 = (const float*)d_in[3];
    const void*  idx = d_in[4];
    const float* W1 = (const float*)d_in[5];
    const float* g1 = (const float*)d_in[6];
    const float* b1 = (const float*)d_in[7];
    const float* W2 = (const float*)d_in[8];
    const float* g2 = (const float*)d_in[9];
    const float* b2 = (const float*)d_in[10];
    float* out = (float*)d_out;

    char* ws = (char*)d_ws;
    float* stats = (float*)(ws + STATS_OFF);
    float* sum1 = stats + 0;     float* ssq1 = stats + 256;
    float* sum2 = stats + 1024;  float* ssq2 = stats + 1280;
    int* flag64 = (int*)(ws + FLAG_OFF);
    unsigned short* W1b = (unsigned short*)(ws + W1B_OFF);
    unsigned short* W2b = (unsigned short*)(ws + W2B_OFF);
    unsigned short* f2t = (unsigned short*)(ws + F2T_OFF);
    unsigned short* xT  = (unsigned short*)(ws + XT_OFF);
    unsigned short* h2  = (unsigned short*)(ws + H2_OFF);

    unsigned short* h1 = (unsigned short*)d_out;  // 67 MB bf16 scratch in d_out

    k_pre<<<577 + 4096 + 4096, 256, 0, stream>>>(idx, flag64, stats, W1, W1b, W2, W2b,
                                                 f2, f2t, f1, xT);
    k_interp<<<MTOT / 8, 256, 0, stream>>>(p1, p2, idx, flag64, f2t, xT);
    k_gemm1<<<dim3(CO / TN, MTOT / TM), 256, 0, stream>>>(xT, W1b, h1, sum1, ssq1);
    k_gemm2<<<dim3(CO / TN, MTOT / TM), 256, 0, stream>>>(h1, W2b, sum1, ssq1, g1, b1, h2, sum2, ssq2);
    k_apply<<<(int)((size_t)out_size / 2048), 256, 0, stream>>>(h2, sum2, ssq2, g2, b2, out);
}